// Round 24
// baseline (64.670 us; speedup 1.0000x reference)
//
#include <hip/hip_runtime.h>

typedef __attribute__((ext_vector_type(8))) _Float16 f16x8;
typedef __attribute__((ext_vector_type(4))) float f32x4;
typedef __attribute__((ext_vector_type(4))) _Float16 h4;
typedef __attribute__((ext_vector_type(2))) __fp16 hw2;
typedef __attribute__((ext_vector_type(2))) float v2f;

#define IMG 512
#define OUT_N 502
#define NPLANE 48
#define NBAND 32             // 16 output rows per band
#define NCG 8                // 64-output-col groups
#define NBLK (NCG * NBAND * NPLANE)   // 12288 blocks
#define HP 40                // hlds row pitch (fp16): 32 rows + 8 pad (16B align)
#define C1c 0.0001f
#define C2c 0.0004f

union H8u { hw2 p[4]; f16x8 v; };
union H4u { hw2 p[2]; h4 v; };

// scalar ssim (edge band only)
__device__ __forceinline__ float ssim_px(float mx, float my, float P, float M) {
    float A = mx*mx, B = my*my, mxy = mx*my;
    float sumsq = 0.5f*(P+M) - A - B;
    float sxy   = 0.25f*(P-M) - mxy;
    float num = (2.f*mxy + C1c) * (2.f*sxy + C2c);
    float den = (A + B + C1c) * (sumsq + C2c);
    return num * __builtin_amdgcn_rcpf(den);
}

// packed-pair ssim: v_pk_*_f32 chain, scalar rcp x2
__device__ __forceinline__ float ssim_px2(v2f mx, v2f my, v2f P, v2f M) {
    v2f A = mx*mx, B = my*my, mxy = mx*my;
    v2f sumsq = 0.5f*(P+M) - A - B;
    v2f sxy   = 0.25f*(P-M) - mxy;
    v2f num = (2.f*mxy + C1c) * (2.f*sxy + C2c);
    v2f den = (A + B + C1c) * (sumsq + C2c);
    return num.x * __builtin_amdgcn_rcpf(den.x)
         + num.y * __builtin_amdgcn_rcpf(den.y);
}

// H-FIRST structure. Block = 16 out rows x 64 out cols, 256 thr (4 waves).
//  H: D = Data(16x32) x Band(32x16), k = image COLS -> each lane's 8
//     k-elements are 8 CONSECUTIVE floats -> 2 dwordx4 loads per source
//     (vs 64 scalar dwords/thread in the V-first structure).
//     8 positions (2 row-chunks x 4 col-tiles), 2 per wave. D holds
//     [img row kg*4+m][out col fi] -> packed b64 store to hlds[f][col][row].
//  V: D2 = Band(16x32) x Hdata(32x16), B-frag = one b128 from
//     hlds[f][16wv+fi][kB] (8 consecutive fp16 rows). D2 = [out row][out col],
//     same epilogue as before. band_f = g[kB+q-fi] serves ALL operand roles
//     (A/B layouts verified absmax 0.0 in R17/R19).
//  Correctness of clamps: V weights vanish for k>=26 -> clamped duplicate
//  rows feed zero-weight slots only (valid out rows use k<=15+10); col clamp
//  cb=min(.,504) only affects k whose weights are zero for valid out cols.
//  LDS 20.6KB -> >=5 blocks/CU; XCD-chunked bijective swizzle keeps each
//  XCD on 6 contiguous planes (R23's +27% lever, halo now 16 shared rows).
__global__ __launch_bounds__(256, 3) void ssim_hf(
    const float* __restrict__ in, const float* __restrict__ tgt,
    const float* __restrict__ w, float* __restrict__ partial)
{
    __shared__ __attribute__((aligned(16))) _Float16 hlds[4][64][HP];
    __shared__ float g1s[16];
    __shared__ float red[4];

    const int tid  = threadIdx.x;
    const int lane = tid & 63;
    const int wv   = tid >> 6;           // wave 0..3
    const int f    = blockIdx.x;
    const int s    = ((f & 7) * (NBLK / 8)) + (f >> 3);   // bijective (12288%8==0)
    const int cg   = s & 7;
    const int band = (s >> 3) & (NBAND - 1);
    const int plane = s >> 8;
    const int r0 = band * 16;
    const int c0 = cg * 64;
    const bool edge = (r0 + 16 > OUT_N);  // block-uniform (band 31)
    const float* __restrict__ ip = in  + (size_t)plane * (IMG*IMG);
    const float* __restrict__ tp = tgt + (size_t)plane * (IMG*IMG);

    const int fi = lane & 15;
    const int kg = lane >> 4;
    const int kB = kg * 8;

    // H positions for this wave: p = chunk*4 + tile
    const int p0 = 2*wv,     c_0 = p0 >> 2, t_0 = p0 & 3;
    const int p1 = 2*wv + 1, c_1 = p1 >> 2, t_1 = p1 & 3;
    const int row0 = min(r0 + 16*c_0 + fi, IMG - 1);
    const int row1 = min(r0 + 16*c_1 + fi, IMG - 1);
    const int cb0  = min(c0 + 16*t_0 + kB, IMG - 8);
    const int cb1  = min(c0 + 16*t_1 + kB, IMG - 8);

    // Batched vector loads (16 dwordx4 total) issued before the preamble
    // barrier -- latency hides under w row-sum + band_f build.
    const f32x4 xa0 = *(const f32x4*)(ip + row0*IMG + cb0);
    const f32x4 xb0 = *(const f32x4*)(ip + row0*IMG + cb0 + 4);
    const f32x4 ya0 = *(const f32x4*)(tp + row0*IMG + cb0);
    const f32x4 yb0 = *(const f32x4*)(tp + row0*IMG + cb0 + 4);
    const f32x4 xa1 = *(const f32x4*)(ip + row1*IMG + cb1);
    const f32x4 xb1 = *(const f32x4*)(ip + row1*IMG + cb1 + 4);
    const f32x4 ya1 = *(const f32x4*)(tp + row1*IMG + cb1);
    const f32x4 yb1 = *(const f32x4*)(tp + row1*IMG + cb1 + 4);

    // 1D factor = row sums of the 2D kernel (exact: w2d = outer(g,g), sum = 1)
    if (tid < 11) {
        float ws_ = 0.f;
        #pragma unroll
        for (int j = 0; j < 11; ++j) ws_ += w[tid*11 + j];
        g1s[tid] = ws_;
    }
    __syncthreads();
    float g[11];
    #pragma unroll
    for (int j = 0; j < 11; ++j)
        g[j] = __int_as_float(__builtin_amdgcn_readfirstlane(__float_as_int(g1s[j])));

    // Banded weight fragment: band_f[q] = g[kB+q - fi] (zero outside 0..10).
    f16x8 band_f;
    #pragma unroll
    for (int q = 0; q < 8; ++q) {
        float wq = 0.f;
        #pragma unroll
        for (int j = 0; j <= 10; ++j)
            wq = (kB + q - fi == j) ? g[j] : wq;
        band_f[q] = (_Float16)wq;
    }

    const f32x4 z = {0.f, 0.f, 0.f, 0.f};

#define HSTORE(F, D) \
    { H4u u_; \
      u_.p[0] = __builtin_amdgcn_cvt_pkrtz((D)[0], (D)[1]); \
      u_.p[1] = __builtin_amdgcn_cvt_pkrtz((D)[2], (D)[3]); \
      *reinterpret_cast<h4*>(&hlds[F][colL][rowL]) = u_.v; }

#define HPROC(XA, XB, YA, YB, CC, TT) \
    { H8u ux, uy; \
      ux.p[0] = __builtin_amdgcn_cvt_pkrtz((XA)[0], (XA)[1]); \
      ux.p[1] = __builtin_amdgcn_cvt_pkrtz((XA)[2], (XA)[3]); \
      ux.p[2] = __builtin_amdgcn_cvt_pkrtz((XB)[0], (XB)[1]); \
      ux.p[3] = __builtin_amdgcn_cvt_pkrtz((XB)[2], (XB)[3]); \
      uy.p[0] = __builtin_amdgcn_cvt_pkrtz((YA)[0], (YA)[1]); \
      uy.p[1] = __builtin_amdgcn_cvt_pkrtz((YA)[2], (YA)[3]); \
      uy.p[2] = __builtin_amdgcn_cvt_pkrtz((YB)[0], (YB)[1]); \
      uy.p[3] = __builtin_amdgcn_cvt_pkrtz((YB)[2], (YB)[3]); \
      f16x8 fX = ux.v, fY = uy.v; \
      f16x8 fS = fX + fY, fD = fX - fY; \
      f16x8 fP = fS * fS, fM = fD * fD; \
      f32x4 dX = __builtin_amdgcn_mfma_f32_16x16x32_f16(fX, band_f, z, 0, 0, 0); \
      f32x4 dY = __builtin_amdgcn_mfma_f32_16x16x32_f16(fY, band_f, z, 0, 0, 0); \
      f32x4 dP = __builtin_amdgcn_mfma_f32_16x16x32_f16(fP, band_f, z, 0, 0, 0); \
      f32x4 dM = __builtin_amdgcn_mfma_f32_16x16x32_f16(fM, band_f, z, 0, 0, 0); \
      const int colL = 16*(TT) + fi;        /* block-local out col */ \
      const int rowL = 16*(CC) + 4*kg;      /* block-local img row */ \
      HSTORE(0, dX) HSTORE(1, dY) HSTORE(2, dP) HSTORE(3, dM) }

    HPROC(xa0, xb0, ya0, yb0, c_0, t_0)
    HPROC(xa1, xb1, ya1, yb1, c_1, t_1)

    __syncthreads();

    // ---- V phase: wave wv -> out cols c0+16wv..+15 ----
    float acc = 0.f;
    {
        const int colL = 16*wv + fi;
        f16x8 bX = *reinterpret_cast<const f16x8*>(&hlds[0][colL][kB]);
        f16x8 bY = *reinterpret_cast<const f16x8*>(&hlds[1][colL][kB]);
        f16x8 bP = *reinterpret_cast<const f16x8*>(&hlds[2][colL][kB]);
        f16x8 bM = *reinterpret_cast<const f16x8*>(&hlds[3][colL][kB]);
        f32x4 dX = __builtin_amdgcn_mfma_f32_16x16x32_f16(band_f, bX, z, 0, 0, 0);
        f32x4 dY = __builtin_amdgcn_mfma_f32_16x16x32_f16(band_f, bY, z, 0, 0, 0);
        f32x4 dP = __builtin_amdgcn_mfma_f32_16x16x32_f16(band_f, bP, z, 0, 0, 0);
        f32x4 dM = __builtin_amdgcn_mfma_f32_16x16x32_f16(band_f, bM, z, 0, 0, 0);
        const int oc = c0 + colL;
        if (oc < OUT_N) {
            if (!edge) {
                v2f mx0 = {dX[0], dX[1]}, my0 = {dY[0], dY[1]};
                v2f P0  = {dP[0], dP[1]}, M0  = {dM[0], dM[1]};
                v2f mx1 = {dX[2], dX[3]}, my1 = {dY[2], dY[3]};
                v2f P1  = {dP[2], dP[3]}, M1  = {dM[2], dM[3]};
                acc += ssim_px2(mx0, my0, P0, M0);
                acc += ssim_px2(mx1, my1, P1, M1);
            } else {
                #pragma unroll
                for (int m = 0; m < 4; ++m) {
                    const int oy = r0 + kg*4 + m;
                    if (oy < OUT_N)
                        acc += ssim_px(dX[m], dY[m], dP[m], dM[m]);
                }
            }
        }
    }

    // block reduction: wave shuffle, then 4 wave-partials through LDS
    #pragma unroll
    for (int off = 32; off > 0; off >>= 1)
        acc += __shfl_down(acc, off, 64);
    if (lane == 0) red[wv] = acc;
    __syncthreads();
    if (tid == 0)
        partial[s] = red[0] + red[1] + red[2] + red[3];
}

// Deterministic final reduction: fixed traversal, double accumulation.
__global__ __launch_bounds__(256) void ssim_final(
    const float* __restrict__ partial, int n, float* __restrict__ out)
{
    __shared__ double red[256];
    double s = 0.0;
    for (int i = threadIdx.x; i < n; i += 256) s += (double)partial[i];
    red[threadIdx.x] = s;
    __syncthreads();
    for (int off = 128; off > 0; off >>= 1) {
        if (threadIdx.x < off) red[threadIdx.x] += red[threadIdx.x + off];
        __syncthreads();
    }
    if (threadIdx.x == 0) out[0] = (float)(1.0 - red[0] / (double)NPLANE);
}

extern "C" void kernel_launch(void* const* d_in, const int* in_sizes, int n_in,
                              void* d_out, int out_size, void* d_ws, size_t ws_size,
                              hipStream_t stream) {
    const float* in  = (const float*)d_in[0];
    const float* tgt = (const float*)d_in[1];
    const float* wt  = (const float*)d_in[2];
    float* out  = (float*)d_out;
    float* part = (float*)d_ws;

    ssim_hf<<<dim3(NBLK), 256, 0, stream>>>(in, tgt, wt, part);
    ssim_final<<<1, 256, 0, stream>>>(part, NBLK, out);
}